// Round 7
// baseline (56.303 us; speedup 1.0000x reference)
//
#include <hip/hip_runtime.h>

// Fused single-kernel GEMV chain for the DCE'd MHA (kv_len==1 => softmax==1):
//   v    = v_w  @ text + v_b              (2048 x 4096, 32 MB)
//   ctx  = wv   @ v    + bv               (2048 x 2048, 16 MB)  wv = in_w rows 4096..6143
//   attn = mo_w @ ctx  + mo_b             (2048 x 2048, 16 MB)
//   out  = visual + o_w @ attn + o_b      (4096 x 2048, 32 MB)
//
// R1-4: __threadfence = whole-L2 invalidate storm (230-250us). R5: uncached
// system-scope for cross-stage data only -> 32.9us. R6: wave specialization
// -> 34.2us (NULL). Remaining ~15us over the stream floor = coherence-point
// contention, shared by R5 and R6:
//   (a) x-vector reads: 1024 blocks x 8KB uncached loads on the SAME 64 LLC
//       lines = 1-2K requests/line, slice-serialized, 1.5-7us per stage.
//   (b) release chain: leafRMW->rootRMW->fanout->poll = 4 LLC hops ~2.4us x3.
// R7 fixes:
//   (a) 8x REPLICATION: producer t0 writes its row pair (packed 8B store) to
//       8 replicas; consumer block b reads replica b&7 -> 8x fewer req/line.
//   (b) DIRECT COUNTER POLL: arrival = 1 RMW on leaf (b>>5) (32 spread
//       lines); wave0 lanes 0-31 each poll one counter, __all(cnt==32) ->
//       release. No root, no fanout: ~1.4us/barrier.
//   (c) clean-queue roles: wave1=W2, wave2=W3+W4cd, wave3=W4ab, wave0=sync+
//       S2+S3 (x2/x3 prefetched right after poll detect, in-wave shfl reduce
//       -> 2 fewer block barriers). Every pre-barrier wait is vmcnt(0) over
//       exactly that wave's own staged data.
// Data path: LDS ping-pong A/B via global_load_lds (proven R3-R6).
// Residency: 1024 blocks = 256 CU x 4 (33 KB LDS), proven R1-R6.

#define ED 2048
#define VD 4096
#define NB 1024
#define NT 256
#define NREP 8
#define BARU 2048   // uints per barrier region: 32 leaf counters @ 64-uint stride

#define SFENCE()    __builtin_amdgcn_sched_barrier(0)
#define BARSYNC()   __builtin_amdgcn_s_barrier()
#define WAIT_VM0()  asm volatile("s_waitcnt vmcnt(0)" ::: "memory")
#define WAIT_LGKM0() asm volatile("s_waitcnt lgkmcnt(0)" ::: "memory")

__device__ __forceinline__ float wave_red(float v) {
#pragma unroll
    for (int off = 32; off > 0; off >>= 1) v += __shfl_down(v, off, 64);
    return v;
}

__device__ __forceinline__ void gload_lds16(const float* g, float* l) {
    __builtin_amdgcn_global_load_lds(
        (const __attribute__((address_space(1))) void*)g,
        (__attribute__((address_space(3))) void*)l, 16, 0, 0);
}

// 16 KB row staged by ALL 4 waves (wave w -> chunks 4w..4w+3).
__device__ __forceinline__ void stage16k(const float* g, float* l, int wid, int lane) {
#pragma unroll
    for (int j = 0; j < 4; ++j) {
        const int c = wid * 4 + j;
        gload_lds16(g + c * 256 + lane * 4, l + c * 256);
    }
}
// 8 KB row staged by ONE wave (8 chunks, program order).
__device__ __forceinline__ void stage8k_1w(const float* g, float* l, int lane) {
#pragma unroll
    for (int c = 0; c < 8; ++c)
        gload_lds16(g + c * 256 + lane * 4, l + c * 256);
}

// Uncached coherence-point ops (no cache maintenance anywhere).
__device__ __forceinline__ float2 load_uc2(const float* p) {
    union { unsigned long long u; float2 f; } c;
    c.u = __hip_atomic_load((const unsigned long long*)p, __ATOMIC_RELAXED,
                            __HIP_MEMORY_SCOPE_SYSTEM);
    return c.f;
}
// Producer: write row pair (r2 even -> 8B aligned) to all NREP replicas.
__device__ __forceinline__ void store_rep(float* rep0, int r2, float v0, float v1) {
    union { float2 f; unsigned long long u; } c;
    c.f = make_float2(v0, v1);
#pragma unroll
    for (int k = 0; k < NREP; ++k)
        __hip_atomic_store((unsigned long long*)(rep0 + k * ED + r2), c.u,
                           __ATOMIC_RELAXED, __HIP_MEMORY_SCOPE_SYSTEM);
}

// t0 only: x-replica stores acked at LLC, then one leaf RMW (32 spread lines).
__device__ __forceinline__ void arrive(unsigned* cnts, int b) {
    WAIT_VM0();
    __hip_atomic_fetch_add(cnts + ((b >> 5) << 6), 1u,
                           __ATOMIC_RELAXED, __HIP_MEMORY_SCOPE_SYSTEM);
}
// wave0 only: lane l < 32 watches leaf l; all counters full -> released.
__device__ __forceinline__ void poll_all(unsigned* cnts, int lane) {
    int spins = 0;
    for (;;) {
        unsigned c = 32u;
        if (lane < 32)
            c = __hip_atomic_load(cnts + lane * 64, __ATOMIC_RELAXED,
                                  __HIP_MEMORY_SCOPE_SYSTEM);
        if (__all(c == 32u)) break;
        if (++spins > (1 << 15)) break;   // visible fail, never hang
        __builtin_amdgcn_s_sleep(8);
    }
}

__global__ __launch_bounds__(NT, 4)
void fused_chain(const float* __restrict__ visual,
                 const float* __restrict__ text,
                 const float* __restrict__ v_w,  const float* __restrict__ v_b,
                 const float* __restrict__ wv,   const float* __restrict__ bv,
                 const float* __restrict__ mo_w, const float* __restrict__ mo_b,
                 const float* __restrict__ o_w,  const float* __restrict__ o_b,
                 float* __restrict__ vrep, float* __restrict__ crep,
                 float* __restrict__ arep, unsigned* __restrict__ flags,
                 float* __restrict__ out)
{
    __shared__ __align__(16) float sA[4096];   // 16 KB slot A
    __shared__ __align__(16) float sB[4096];   // 16 KB slot B
    __shared__ float red[16];

    const int t    = threadIdx.x;
    const int b    = blockIdx.x;
    const int lane = t & 63;
    const int wid  = t >> 6;
    const int r2   = 2 * b;
    const int r4   = 4 * b;
    const int rep  = b & (NREP - 1);

    const float4* A4 = (const float4*)sA;
    const float4* B4 = (const float4*)sB;

    // ---- prologue: biases/residual (t0), W1 -> A,B (all waves), x1 ----
    float bi10=0.f, bi11=0.f, bi20=0.f, bi21=0.f, bi30=0.f, bi31=0.f;
    float bo0=0.f, bo1=0.f, bo2=0.f, bo3=0.f;
    if (t == 0) {
        bi10 = v_b[r2];  bi11 = v_b[r2+1];
        bi20 = bv[r2];   bi21 = bv[r2+1];
        bi30 = mo_b[r2]; bi31 = mo_b[r2+1];
        bo0 = o_b[r4]   + visual[r4];
        bo1 = o_b[r4+1] + visual[r4+1];
        bo2 = o_b[r4+2] + visual[r4+2];
        bo3 = o_b[r4+3] + visual[r4+3];
    }
    stage16k(v_w + (size_t)r2 * VD,       sA, wid, lane);
    stage16k(v_w + (size_t)(r2 + 1) * VD, sB, wid, lane);
    const float4* x1p = (const float4*)text;
    float4 x1[4];
#pragma unroll
    for (int j = 0; j < 4; ++j) x1[j] = x1p[t + j * NT];

    WAIT_VM0();                    // every wave: its own W1 chunks + x1 + biases
    SFENCE(); BARSYNC(); SFENCE(); // BAR1: S1 data ready

    // ---- stage 1: v = v_w @ text + v_b (all waves) ----
    float a0 = 0.f, a1 = 0.f;
#pragma unroll
    for (int j = 0; j < 4; ++j) {
        float4 wa = A4[t + j * NT], wb = B4[t + j * NT];
        a0 = fmaf(wa.x, x1[j].x, a0); a0 = fmaf(wa.y, x1[j].y, a0);
        a0 = fmaf(wa.z, x1[j].z, a0); a0 = fmaf(wa.w, x1[j].w, a0);
        a1 = fmaf(wb.x, x1[j].x, a1); a1 = fmaf(wb.y, x1[j].y, a1);
        a1 = fmaf(wb.z, x1[j].z, a1); a1 = fmaf(wb.w, x1[j].w, a1);
    }
    a0 = wave_red(a0); a1 = wave_red(a1);
    if (lane == 0) { red[wid] = a0; red[8 + wid] = a1; }
    WAIT_LGKM0();
    SFENCE(); BARSYNC(); SFENCE(); // BAR2: red ready, S1 LDS reads done

    // ---- boundary 1: publish v, stage W2 (wave1) / W3 (wave2), sync ----
    if (wid == 1) {                                  // W2 -> sA
        stage8k_1w(wv + (size_t)r2 * ED,       sA,        lane);
        stage8k_1w(wv + (size_t)(r2 + 1) * ED, sA + 2048, lane);
    }
    if (wid == 2) {                                  // W3 -> sB
        stage8k_1w(mo_w + (size_t)r2 * ED,       sB,        lane);
        stage8k_1w(mo_w + (size_t)(r2 + 1) * ED, sB + 2048, lane);
    }
    if (t == 0) {
        store_rep(vrep, r2,
                  red[0] + red[1] + red[2] + red[3] + bi10,
                  red[8] + red[9] + red[10] + red[11] + bi11);
        arrive(flags, b);
    }
    float2 x2a[8], x2b[8];
    if (wid == 0) {
        poll_all(flags, lane);                       // release1 detected
        const float* xr = vrep + rep * ED;           // prefetch x2 (clean queue)
#pragma unroll
        for (int j = 0; j < 8; ++j) {
            const float* p = xr + 4 * (lane + 64 * j);
            x2a[j] = load_uc2(p); x2b[j] = load_uc2(p + 2);
        }
    }
    if (wid == 1) { WAIT_VM0(); }                    // W2 landed
    SFENCE(); BARSYNC(); SFENCE(); // BAR3: release1 + W2 in LDS

    // ---- stage 2: ctx = wv @ v + bv (wave0 alone; 2 rows x 2048) ----
    if (wid == 0) {
        WAIT_VM0(); SFENCE();                        // x2 (only outstanding)
        float s0 = 0.f, s1 = 0.f;
#pragma unroll
        for (int j = 0; j < 8; ++j) {
            float4 wa = A4[lane + 64 * j];
            float4 wb = A4[512 + lane + 64 * j];
            s0 = fmaf(wa.x, x2a[j].x, s0); s0 = fmaf(wa.y, x2a[j].y, s0);
            s0 = fmaf(wa.z, x2b[j].x, s0); s0 = fmaf(wa.w, x2b[j].y, s0);
            s1 = fmaf(wb.x, x2a[j].x, s1); s1 = fmaf(wb.y, x2a[j].y, s1);
            s1 = fmaf(wb.z, x2b[j].x, s1); s1 = fmaf(wb.w, x2b[j].y, s1);
        }
        s0 = wave_red(s0); s1 = wave_red(s1);
        if (t == 0) {
            store_rep(crep, r2, s0 + bi20, s1 + bi21);
            arrive(flags + BARU, b);
        }
        poll_all(flags + BARU, lane);                // release2 detected
        const float* xr = crep + rep * ED;           // prefetch x3
#pragma unroll
        for (int j = 0; j < 8; ++j) {
            const float* p = xr + 4 * (lane + 64 * j);
            x2a[j] = load_uc2(p); x2b[j] = load_uc2(p + 2);
        }
    }
    if (wid == 2) { WAIT_VM0(); }                    // W3 landed
    SFENCE(); BARSYNC(); SFENCE(); // BAR4: release2 + W3 in LDS + sA free

    // ---- stage 3: attn = mo_w @ ctx + mo_b (wave0) | W4ab (wave3 -> sA) ----
    if (wid == 3) {
        stage8k_1w(o_w + (size_t)r4 * ED,       sA,        lane);
        stage8k_1w(o_w + (size_t)(r4 + 1) * ED, sA + 2048, lane);
    }
    if (wid == 0) {
        WAIT_VM0(); SFENCE();                        // x3
        float s0 = 0.f, s1 = 0.f;
#pragma unroll
        for (int j = 0; j < 8; ++j) {
            float4 wa = B4[lane + 64 * j];
            float4 wb = B4[512 + lane + 64 * j];
            s0 = fmaf(wa.x, x2a[j].x, s0); s0 = fmaf(wa.y, x2a[j].y, s0);
            s0 = fmaf(wa.z, x2b[j].x, s0); s0 = fmaf(wa.w, x2b[j].y, s0);
            s1 = fmaf(wb.x, x2a[j].x, s1); s1 = fmaf(wb.y, x2a[j].y, s1);
            s1 = fmaf(wb.z, x2b[j].x, s1); s1 = fmaf(wb.w, x2b[j].y, s1);
        }
        s0 = wave_red(s0); s1 = wave_red(s1);
        if (t == 0) {
            store_rep(arep, r2, s0 + bi30, s1 + bi31);
            arrive(flags + 2 * BARU, b);
        }
        poll_all(flags + 2 * BARU, lane);            // release3 detected
    }
    SFENCE(); BARSYNC(); SFENCE(); // BAR5: release3 + S3's sB reads done

    // ---- boundary 3: W4cd (wave2 -> sB), x4 (all), drain, sync ----
    if (wid == 2) {
        stage8k_1w(o_w + (size_t)(r4 + 2) * ED, sB,        lane);
        stage8k_1w(o_w + (size_t)(r4 + 3) * ED, sB + 2048, lane);
    }
    const float* xr4 = arep + rep * ED;
    float2 xl[2], xh[2];
#pragma unroll
    for (int j = 0; j < 2; ++j) {
        const float* p = xr4 + 4 * (t + 256 * j);
        xl[j] = load_uc2(p); xh[j] = load_uc2(p + 2);
    }
    WAIT_VM0();                    // wave2: W4cd+x4; wave3: W4ab+x4; others: x4
    SFENCE(); BARSYNC(); SFENCE(); // BAR6: all W4 in LDS, x4 in regs

    // ---- stage 4: out = visual + o_w @ attn + o_b (all waves, 4 rows) ----
    float c0 = 0.f, c1 = 0.f, c2 = 0.f, c3 = 0.f;
#pragma unroll
    for (int j = 0; j < 2; ++j) {
        float4 wa = A4[t + j * NT], wb = A4[512 + t + j * NT];
        float4 wc = B4[t + j * NT], wd = B4[512 + t + j * NT];
        c0 = fmaf(wa.x, xl[j].x, c0); c0 = fmaf(wa.y, xl[j].y, c0);
        c0 = fmaf(wa.z, xh[j].x, c0); c0 = fmaf(wa.w, xh[j].y, c0);
        c1 = fmaf(wb.x, xl[j].x, c1); c1 = fmaf(wb.y, xl[j].y, c1);
        c1 = fmaf(wb.z, xh[j].x, c1); c1 = fmaf(wb.w, xh[j].y, c1);
        c2 = fmaf(wc.x, xl[j].x, c2); c2 = fmaf(wc.y, xl[j].y, c2);
        c2 = fmaf(wc.z, xh[j].x, c2); c2 = fmaf(wc.w, xh[j].y, c2);
        c3 = fmaf(wd.x, xl[j].x, c3); c3 = fmaf(wd.y, xl[j].y, c3);
        c3 = fmaf(wd.z, xh[j].x, c3); c3 = fmaf(wd.w, xh[j].y, c3);
    }
    c0 = wave_red(c0); c1 = wave_red(c1); c2 = wave_red(c2); c3 = wave_red(c3);
    if (lane == 0) {
        red[wid] = c0; red[4 + wid] = c1; red[8 + wid] = c2; red[12 + wid] = c3;
    }
    WAIT_LGKM0();
    SFENCE(); BARSYNC(); SFENCE(); // BAR7
    if (t == 0) {
        out[r4]     = red[0]  + red[1]  + red[2]  + red[3]  + bo0;
        out[r4 + 1] = red[4]  + red[5]  + red[6]  + red[7]  + bo1;
        out[r4 + 2] = red[8]  + red[9]  + red[10] + red[11] + bo2;
        out[r4 + 3] = red[12] + red[13] + red[14] + red[15] + bo3;
    }
}

extern "C" void kernel_launch(void* const* d_in, const int* in_sizes, int n_in,
                              void* d_out, int out_size, void* d_ws, size_t ws_size,
                              hipStream_t stream) {
    (void)in_sizes; (void)n_in; (void)out_size; (void)ws_size;
    const float* visual = (const float*)d_in[0];   // [4096]
    const float* text   = (const float*)d_in[1];   // [4096]
    // d_in[2..5] = q_w, q_b, k_w, k_b -> dead (softmax over single key == 1)
    const float* v_w  = (const float*)d_in[6];     // [2048, 4096]
    const float* v_b  = (const float*)d_in[7];     // [2048]
    const float* in_w = (const float*)d_in[8];     // [6144, 2048]
    const float* in_b = (const float*)d_in[9];     // [6144]
    const float* mo_w = (const float*)d_in[10];    // [2048, 2048]
    const float* mo_b = (const float*)d_in[11];    // [2048]
    const float* o_w  = (const float*)d_in[12];    // [4096, 2048]
    const float* o_b  = (const float*)d_in[13];    // [4096]
    float* out = (float*)d_out;                    // [4096]

    const float* wv = in_w + (size_t)2 * ED * ED;  // in_w rows 4096..6143
    const float* bv = in_b + 2 * ED;

    float* ws   = (float*)d_ws;
    float* vrep = ws;                       // [8][2048]
    float* crep = ws + NREP * ED;           // [8][2048]
    float* arep = ws + 2 * NREP * ED;       // [8][2048]
    unsigned* flags = (unsigned*)(ws + 3 * NREP * ED);   // 3 x BARU uints

    // Workspace is poisoned between iterations -> barrier state must be zeroed.
    hipMemsetAsync(flags, 0, 3 * BARU * sizeof(unsigned), stream);
    fused_chain<<<NB, NT, 0, stream>>>(visual, text, v_w, v_b, wv, bv,
                                       mo_w, mo_b, o_w, o_b,
                                       vrep, crep, arep, flags, out);
}

// Round 8
// 32.231 us; speedup vs baseline: 1.7469x; 1.7469x over previous
//
#include <hip/hip_runtime.h>

// Fused single-kernel GEMV chain for the DCE'd MHA (kv_len==1 => softmax==1):
//   v    = v_w  @ text + v_b              (2048 x 4096, 32 MB)
//   ctx  = wv   @ v    + bv               (2048 x 2048, 16 MB)  wv = in_w rows 4096..6143
//   attn = mo_w @ ctx  + mo_b             (2048 x 2048, 16 MB)
//   out  = visual + o_w @ attn + o_b      (4096 x 2048, 32 MB)
//
// History: R1-4 __threadfence = whole-L2 invalidate storm (230-250us).
// R5: uncached system-scope for cross-stage data only -> 32.9us (best fused).
// R6: wave specialization -> null. R7: direct-counter poll made every block
// poll ALL 32 counter lines (32x R5's poll traffic) -> LLC slices saturated,
// 56us + HBM BW drop. Positive ID: uncached-request rate per LLC line is the
// governing resource.
// Residual in R5: x-vector reads = 1024 blocks x 8KB uncached on the SAME 64
// lines = ~2048 line-requests/line/stage (slice-serialized, ~4-8us) x3 stages.
//
// R8 = R5 + exactly two fixes:
//  (1) 8x replication of vvec/ctx/attn: producer t0 writes its row pair as a
//      packed 8B store to 8 replicas (8KB apart); consumer block b reads
//      replica b&7 -> 8x fewer requests per LLC line (~1us/stage).
//  (2) arrive hoisted BEFORE the staging issues at each boundary, so t0's
//      vmcnt(0) waits only on its 8B replica stores, not on its own wave's
//      just-issued staging chunks landing (~1-2us earlier arrival).
// Everything else byte-identical to R5: leaf/root/fan-out barrier (spread
// 256B lines, own-leaf poll, s_sleep(4)), LDS ping-pong A/B global_load_lds
// staging issued before the spin, __syncthreads as the post-release drain.
// Residency: 1024 blocks = 256 CU x 4 (33 KB LDS), proven R1-R7.

#define ED 2048
#define VD 4096
#define NB 1024
#define NT 256
#define NREP 8

// Barrier region layout (uints): leafCnt[l] @ l*64, rootCnt @ 2048,
// leafRel[l] @ 2112 + l*64.  Region size 4224 uints = 16896 B per barrier.
#define BAR_U 4224

__device__ __forceinline__ float wave_red(float v) {
#pragma unroll
    for (int off = 32; off > 0; off >>= 1) v += __shfl_down(v, off, 64);
    return v;
}

__device__ __forceinline__ void gload_lds16(const float* g, float* l) {
    __builtin_amdgcn_global_load_lds(
        (const __attribute__((address_space(1))) void*)g,
        (__attribute__((address_space(3))) void*)l, 16, 0, 0);
}

// Stage one 16 KB row (4096 floats): 16 chunks of 1 KB; wave w -> chunks 4w..4w+3.
__device__ __forceinline__ void stage16k(const float* g, float* l, int wid, int lane) {
#pragma unroll
    for (int j = 0; j < 4; ++j) {
        const int c = wid * 4 + j;
        gload_lds16(g + c * 256 + lane * 4, l + c * 256);
    }
}

// Stage one 8 KB row (2048 floats): 8 chunks; wave w -> chunks 2w..2w+1.
__device__ __forceinline__ void stage8k(const float* g, float* l, int wid, int lane) {
#pragma unroll
    for (int j = 0; j < 2; ++j) {
        const int c = wid * 2 + j;
        gload_lds16(g + c * 256 + lane * 4, l + c * 256);
    }
}

// Uncached (coherence-point) ops. No cache maintenance anywhere in the kernel.
__device__ __forceinline__ float2 load_uc2(const float* p) {
    union { unsigned long long u; float2 f; } c;
    c.u = __hip_atomic_load((const unsigned long long*)p, __ATOMIC_RELAXED,
                            __HIP_MEMORY_SCOPE_SYSTEM);
    return c.f;
}
// Producer: write row pair (r2 even -> 8B aligned) to all NREP replicas.
__device__ __forceinline__ void store_rep(float* rep0, int r2, float v0, float v1) {
    union { float2 f; unsigned long long u; } c;
    c.f = make_float2(v0, v1);
#pragma unroll
    for (int k = 0; k < NREP; ++k)
        __hip_atomic_store((unsigned long long*)(rep0 + k * ED + r2), c.u,
                           __ATOMIC_RELAXED, __HIP_MEMORY_SCOPE_SYSTEM);
}

// t0 only; called BEFORE any staging issue at the boundary, so vmcnt(0)
// covers only the replica stores. Leaf/root RMW returns force LLC ordering.
__device__ __forceinline__ void barrier_arrive(unsigned* base, int b) {
    if (threadIdx.x == 0) {
        asm volatile("s_waitcnt vmcnt(0)" ::: "memory");   // replica stores acked
        if (__hip_atomic_fetch_add(base + ((b >> 5) << 6), 1u,
                __ATOMIC_RELAXED, __HIP_MEMORY_SCOPE_SYSTEM) == 31u) {
            if (__hip_atomic_fetch_add(base + 2048, 1u,
                    __ATOMIC_RELAXED, __HIP_MEMORY_SCOPE_SYSTEM) == 31u) {
#pragma unroll
                for (int l = 0; l < 32; ++l)
                    __hip_atomic_store(base + 2112 + l * 64, 1u,
                                       __ATOMIC_RELAXED, __HIP_MEMORY_SCOPE_SYSTEM);
            }
        }
    }
}

__device__ __forceinline__ void barrier_wait(unsigned* base, int b) {
    if (threadIdx.x == 0) {
        unsigned* rel = base + 2112 + ((b >> 5) << 6);   // own leaf: 32 pollers/line
        int spins = 0;
        while (__hip_atomic_load(rel, __ATOMIC_RELAXED,
                                 __HIP_MEMORY_SCOPE_SYSTEM) == 0u) {
            __builtin_amdgcn_s_sleep(4);
            if (++spins > (1 << 17)) break;   // visible fail, never hang
        }
    }
    __syncthreads();       // releases block; drains vmcnt for staged LDS data
}

__global__ __launch_bounds__(NT, 4)
void fused_chain(const float* __restrict__ visual,
                 const float* __restrict__ text,
                 const float* __restrict__ v_w,  const float* __restrict__ v_b,
                 const float* __restrict__ wv,   const float* __restrict__ bv,
                 const float* __restrict__ mo_w, const float* __restrict__ mo_b,
                 const float* __restrict__ o_w,  const float* __restrict__ o_b,
                 float* __restrict__ vrep, float* __restrict__ crep,
                 float* __restrict__ arep, unsigned* __restrict__ flags,
                 float* __restrict__ out)
{
    __shared__ __align__(16) float sA[4096];   // 16 KB slot A
    __shared__ __align__(16) float sB[4096];   // 16 KB slot B
    __shared__ float red[16];

    const int t    = threadIdx.x;
    const int b    = blockIdx.x;
    const int lane = t & 63;
    const int wid  = t >> 6;
    const int r2   = 2 * b;                  // row pair, stages 1-3
    const int r4   = 4 * b;                  // row quad, stage 4
    const int rep  = b & (NREP - 1);         // this block's x replica

    const float4* A4 = (const float4*)sA;
    const float4* B4 = (const float4*)sB;

    // ---- stage W1 rows -> A,B; x1 (kernel input, cached) -> regs ----
    stage16k(v_w + (size_t)r2 * VD,       sA, wid, lane);
    stage16k(v_w + (size_t)(r2 + 1) * VD, sB, wid, lane);
    const float4* x1p = (const float4*)text;
    float4 x1[4];
#pragma unroll
    for (int j = 0; j < 4; ++j) x1[j] = x1p[t + j * NT];
    __syncthreads();                       // drains vmcnt: LDS + x1 ready

    // ---- stage 1: v = v_w @ text + v_b ----
    float a0 = 0.f, a1 = 0.f;
#pragma unroll
    for (int j = 0; j < 4; ++j) {
        float4 wa = A4[t + j * NT], wb = B4[t + j * NT];
        a0 = fmaf(wa.x, x1[j].x, a0); a0 = fmaf(wa.y, x1[j].y, a0);
        a0 = fmaf(wa.z, x1[j].z, a0); a0 = fmaf(wa.w, x1[j].w, a0);
        a1 = fmaf(wb.x, x1[j].x, a1); a1 = fmaf(wb.y, x1[j].y, a1);
        a1 = fmaf(wb.z, x1[j].z, a1); a1 = fmaf(wb.w, x1[j].w, a1);
    }
    float bi0 = 0.f, bi1 = 0.f;
    if (t == 0) { bi0 = v_b[r2]; bi1 = v_b[r2 + 1]; }   // overlaps reduce
    a0 = wave_red(a0); a1 = wave_red(a1);
    if (lane == 0) { red[wid] = a0; red[8 + wid] = a1; }
    __syncthreads();                       // WAR guard: S1 reads of A/B done

    // ---- boundary 1: publish v (replicated), arrive FIRST, then stage ----
    if (t == 0) {
        store_rep(vrep, r2,
                  red[0] + red[1] + red[2] + red[3] + bi0,
                  red[8] + red[9] + red[10] + red[11] + bi1);
    }
    barrier_arrive(flags, b);

    // ---- W2 -> A, W3 -> B: in flight during the bar1 spin ----
    stage8k(wv + (size_t)r2 * ED,         sA,        wid, lane);
    stage8k(wv + (size_t)(r2 + 1) * ED,   sA + 2048, wid, lane);
    stage8k(mo_w + (size_t)r2 * ED,       sB,        wid, lane);
    stage8k(mo_w + (size_t)(r2 + 1) * ED, sB + 2048, wid, lane);

    barrier_wait(flags, b);

    // ---- stage 2: ctx = wv @ v + bv (weights in LDS slot A) ----
    const float* xr2 = vrep + rep * ED;
    float2 xl[2], xh[2];
#pragma unroll
    for (int j = 0; j < 2; ++j) {
        const float* p = xr2 + 4 * (t + j * NT);
        xl[j] = load_uc2(p); xh[j] = load_uc2(p + 2);
    }
    a0 = 0.f; a1 = 0.f;
#pragma unroll
    for (int j = 0; j < 2; ++j) {
        float4 wa = A4[t + j * NT], wb = A4[512 + t + j * NT];
        a0 = fmaf(wa.x, xl[j].x, a0); a0 = fmaf(wa.y, xl[j].y, a0);
        a0 = fmaf(wa.z, xh[j].x, a0); a0 = fmaf(wa.w, xh[j].y, a0);
        a1 = fmaf(wb.x, xl[j].x, a1); a1 = fmaf(wb.y, xl[j].y, a1);
        a1 = fmaf(wb.z, xh[j].x, a1); a1 = fmaf(wb.w, xh[j].y, a1);
    }
    if (t == 0) { bi0 = bv[r2]; bi1 = bv[r2 + 1]; }
    a0 = wave_red(a0); a1 = wave_red(a1);
    if (lane == 0) { red[wid] = a0; red[8 + wid] = a1; }
    __syncthreads();                       // WAR guard: S2 reads of A done

    // ---- boundary 2: publish ctx, arrive, then stage W4ab -> A ----
    if (t == 0) {
        store_rep(crep, r2,
                  red[0] + red[1] + red[2] + red[3] + bi0,
                  red[8] + red[9] + red[10] + red[11] + bi1);
    }
    barrier_arrive(flags + BAR_U, b);

    stage8k(o_w + (size_t)r4 * ED,       sA,        wid, lane);
    stage8k(o_w + (size_t)(r4 + 1) * ED, sA + 2048, wid, lane);

    barrier_wait(flags + BAR_U, b);

    // ---- stage 3: attn = mo_w @ ctx + mo_b (weights in LDS slot B) ----
    const float* xr3 = crep + rep * ED;
#pragma unroll
    for (int j = 0; j < 2; ++j) {
        const float* p = xr3 + 4 * (t + j * NT);
        xl[j] = load_uc2(p); xh[j] = load_uc2(p + 2);
    }
    a0 = 0.f; a1 = 0.f;
#pragma unroll
    for (int j = 0; j < 2; ++j) {
        float4 wa = B4[t + j * NT], wb = B4[512 + t + j * NT];
        a0 = fmaf(wa.x, xl[j].x, a0); a0 = fmaf(wa.y, xl[j].y, a0);
        a0 = fmaf(wa.z, xh[j].x, a0); a0 = fmaf(wa.w, xh[j].y, a0);
        a1 = fmaf(wb.x, xl[j].x, a1); a1 = fmaf(wb.y, xl[j].y, a1);
        a1 = fmaf(wb.z, xh[j].x, a1); a1 = fmaf(wb.w, xh[j].y, a1);
    }
    if (t == 0) { bi0 = mo_b[r2]; bi1 = mo_b[r2 + 1]; }
    a0 = wave_red(a0); a1 = wave_red(a1);
    if (lane == 0) { red[wid] = a0; red[8 + wid] = a1; }
    __syncthreads();                       // WAR guard: S3 reads of B done

    // ---- boundary 3: publish attn, arrive, then stage W4cd -> B ----
    if (t == 0) {
        store_rep(arep, r2,
                  red[0] + red[1] + red[2] + red[3] + bi0,
                  red[8] + red[9] + red[10] + red[11] + bi1);
    }
    barrier_arrive(flags + 2 * BAR_U, b);

    stage8k(o_w + (size_t)(r4 + 2) * ED, sB,        wid, lane);
    stage8k(o_w + (size_t)(r4 + 3) * ED, sB + 2048, wid, lane);

    barrier_wait(flags + 2 * BAR_U, b);

    // ---- stage 4: out = visual + o_w @ attn + o_b (4 rows from A+B) ----
    const float* xr4 = arep + rep * ED;
#pragma unroll
    for (int j = 0; j < 2; ++j) {
        const float* p = xr4 + 4 * (t + j * NT);
        xl[j] = load_uc2(p); xh[j] = load_uc2(p + 2);
    }
    float c0 = 0.f, c1 = 0.f, c2 = 0.f, c3 = 0.f;
#pragma unroll
    for (int j = 0; j < 2; ++j) {
        float4 wa = A4[t + j * NT], wb = A4[512 + t + j * NT];
        float4 wc = B4[t + j * NT], wd = B4[512 + t + j * NT];
        c0 = fmaf(wa.x, xl[j].x, c0); c0 = fmaf(wa.y, xl[j].y, c0);
        c0 = fmaf(wa.z, xh[j].x, c0); c0 = fmaf(wa.w, xh[j].y, c0);
        c1 = fmaf(wb.x, xl[j].x, c1); c1 = fmaf(wb.y, xl[j].y, c1);
        c1 = fmaf(wb.z, xh[j].x, c1); c1 = fmaf(wb.w, xh[j].y, c1);
        c2 = fmaf(wc.x, xl[j].x, c2); c2 = fmaf(wc.y, xl[j].y, c2);
        c2 = fmaf(wc.z, xh[j].x, c2); c2 = fmaf(wc.w, xh[j].y, c2);
        c3 = fmaf(wd.x, xl[j].x, c3); c3 = fmaf(wd.y, xl[j].y, c3);
        c3 = fmaf(wd.z, xh[j].x, c3); c3 = fmaf(wd.w, xh[j].y, c3);
    }
    float bo0 = 0.f, bo1 = 0.f, bo2 = 0.f, bo3 = 0.f;
    if (t == 0) {
        bo0 = o_b[r4] + visual[r4];
        bo1 = o_b[r4 + 1] + visual[r4 + 1];
        bo2 = o_b[r4 + 2] + visual[r4 + 2];
        bo3 = o_b[r4 + 3] + visual[r4 + 3];
    }
    c0 = wave_red(c0); c1 = wave_red(c1); c2 = wave_red(c2); c3 = wave_red(c3);
    if (lane == 0) {
        red[wid] = c0; red[4 + wid] = c1; red[8 + wid] = c2; red[12 + wid] = c3;
    }
    __syncthreads();
    if (t == 0) {
        out[r4]     = red[0]  + red[1]  + red[2]  + red[3]  + bo0;
        out[r4 + 1] = red[4]  + red[5]  + red[6]  + red[7]  + bo1;
        out[r4 + 2] = red[8]  + red[9]  + red[10] + red[11] + bo2;
        out[r4 + 3] = red[12] + red[13] + red[14] + red[15] + bo3;
    }
}

extern "C" void kernel_launch(void* const* d_in, const int* in_sizes, int n_in,
                              void* d_out, int out_size, void* d_ws, size_t ws_size,
                              hipStream_t stream) {
    (void)in_sizes; (void)n_in; (void)out_size; (void)ws_size;
    const float* visual = (const float*)d_in[0];   // [4096]
    const float* text   = (const float*)d_in[1];   // [4096]
    // d_in[2..5] = q_w, q_b, k_w, k_b -> dead (softmax over single key == 1)
    const float* v_w  = (const float*)d_in[6];     // [2048, 4096]
    const float* v_b  = (const float*)d_in[7];     // [2048]
    const float* in_w = (const float*)d_in[8];     // [6144, 2048]
    const float* in_b = (const float*)d_in[9];     // [6144]
    const float* mo_w = (const float*)d_in[10];    // [2048, 2048]
    const float* mo_b = (const float*)d_in[11];    // [2048]
    const float* o_w  = (const float*)d_in[12];    // [4096, 2048]
    const float* o_b  = (const float*)d_in[13];    // [4096]
    float* out = (float*)d_out;                    // [4096]

    const float* wv = in_w + (size_t)2 * ED * ED;  // in_w rows 4096..6143
    const float* bv = in_b + 2 * ED;

    float* ws   = (float*)d_ws;
    float* vrep = ws;                       // [8][2048]
    float* crep = ws + NREP * ED;           // [8][2048]
    float* arep = ws + 2 * NREP * ED;       // [8][2048]
    unsigned* flags = (unsigned*)(ws + 3 * NREP * ED);   // 3 x BAR_U uints

    // Workspace is poisoned between iterations -> barrier state must be zeroed.
    hipMemsetAsync(flags, 0, 3 * BAR_U * sizeof(unsigned), stream);
    fused_chain<<<NB, NT, 0, stream>>>(visual, text, v_w, v_b, wv, bv,
                                       mo_w, mo_b, o_w, o_b,
                                       vrep, crep, arep, flags, out);
}